// Round 4
// baseline (4675.602 us; speedup 1.0000x reference)
//
#include <hip/hip_runtime.h>
#include <hip/hip_bf16.h>
#include <stdint.h>

// Sparse autoencoder: z1 = x@W^T + b_enc ; top-k(3276) mask ; z2 = a1@W + b_dec
// Encoder = single bf16 MFMA GEMM (approx); exact top-k selection restored via
// band recompute near the threshold. Both GEMMs: 256x256 tile, 8-phase
// schedule with counted vmcnt (T2+T3+T4+T5), 8 waves, 128 KiB dbuf LDS.

#define DIM      4096
#define BATCH    4096
#define NROWS_W  32768
#define KCNT     3276
#define DELTA    0.010f
#define ROWCAP   384
#define HCAP     64

typedef __bf16 bf16x8 __attribute__((ext_vector_type(8)));
typedef __bf16 bf16x4 __attribute__((ext_vector_type(4)));
typedef float  f32x4  __attribute__((ext_vector_type(4)));

__device__ __forceinline__ void gload_lds16(const void* g, void* l) {
  __builtin_amdgcn_global_load_lds(
      (const __attribute__((address_space(1))) void*)g,
      (__attribute__((address_space(3))) void*)l, 16, 0, 0);
}

// ---------------- split fp32 -> bf16 hi + bf16 lo ----------------
__global__ void k_split(const float* __restrict__ s, __bf16* __restrict__ hi,
                        __bf16* __restrict__ lo, int n4) {
  int i = blockIdx.x * 256 + threadIdx.x;
  const int stride = gridDim.x * 256;
  for (; i < n4; i += stride) {
    f32x4 v = ((const f32x4*)s)[i];
    bf16x4 h, l;
#pragma unroll
    for (int j = 0; j < 4; ++j) {
      __bf16 hb = (__bf16)v[j];
      h[j] = hb;
      l[j] = (__bf16)(v[j] - (float)hb);
    }
    ((bf16x4*)hi)[i] = h;
    ((bf16x4*)lo)[i] = l;
  }
}

// ---------------- bf16 transpose (tiled) ----------------
__global__ void k_transpose(const __bf16* __restrict__ src, __bf16* __restrict__ dst,
                            int R, int C) {
  __shared__ __bf16 t[32][33];
  const int c0 = blockIdx.x * 32, r0 = blockIdx.y * 32;
  for (int rr = threadIdx.y; rr < 32; rr += 8)
    t[rr][threadIdx.x] = src[(long)(r0 + rr) * C + c0 + threadIdx.x];
  __syncthreads();
  for (int rr = threadIdx.y; rr < 32; rr += 8)
    dst[(long)(c0 + rr) * R + r0 + threadIdx.x] = t[threadIdx.x][rr];
}

// =============== 256x256 8-phase GEMM: C = A[M,K] * B^T[N,K] + bias ===========
// 8 waves as 4(M) x 2(N); wave tile 64x128. BK=64. LDS double-buffered,
// T2 XOR-swizzle (pre-swizzled global source, swizzled ds_read).
// Stage units: A quarters q=0..3 (64 rows, 8KB), B pairs pr=0..3 (64 cols, 8KB);
// 2 units per phase, counted vmcnt(4/4/2) at phases 1/2/3 (never 0).

#define VM4 { asm volatile("s_waitcnt vmcnt(4)" ::: "memory"); }
#define VM2 { asm volatile("s_waitcnt vmcnt(2)" ::: "memory"); }
#define VM0 { }

#define PH(CUR, P, SCODE, WCODE)                                                  \
  {                                                                               \
    bf16x8 bg[2][2];                                                              \
    _Pragma("unroll") for (int n_ = 0; n_ < 2; ++n_) {                            \
      const int col_ = wn * 128 + (P) * 32 + n_ * 16 + lr;                        \
      _Pragma("unroll") for (int kc_ = 0; kc_ < 2; ++kc_)                         \
        bg[n_][kc_] = *(const bf16x8*)((const char*)sB[CUR] + col_ * 128 +        \
                                       ((kc_ * 64 + lk * 16) ^ swz));             \
    }                                                                             \
    SCODE;                                                                        \
    WCODE;                                                                        \
    __builtin_amdgcn_s_barrier();                                                 \
    __builtin_amdgcn_s_setprio(1);                                                \
    _Pragma("unroll") for (int m_ = 0; m_ < 4; ++m_)                              \
      _Pragma("unroll") for (int n_ = 0; n_ < 2; ++n_)                            \
        _Pragma("unroll") for (int kc_ = 0; kc_ < 2; ++kc_)                       \
          acc[m_][(P) * 2 + n_] = __builtin_amdgcn_mfma_f32_16x16x32_bf16(        \
              af[m_][kc_], bg[n_][kc_], acc[m_][(P) * 2 + n_], 0, 0, 0);          \
    __builtin_amdgcn_s_setprio(0);                                                \
    __builtin_amdgcn_s_barrier();                                                 \
  }

#define TILE(CUR, S0, S1, S2, S3)                                                 \
  {                                                                               \
    bf16x8 af[4][2];                                                              \
    _Pragma("unroll") for (int m_ = 0; m_ < 4; ++m_) {                            \
      const int row_ = wm * 64 + m_ * 16 + lr;                                    \
      _Pragma("unroll") for (int kc_ = 0; kc_ < 2; ++kc_)                         \
        af[m_][kc_] = *(const bf16x8*)((const char*)sA[CUR] + row_ * 128 +        \
                                       ((kc_ * 64 + lk * 16) ^ swz));             \
    }                                                                             \
    PH(CUR, 0, S0, VM0)                                                           \
    PH(CUR, 1, S1, VM4)                                                           \
    PH(CUR, 2, S2, VM4)                                                           \
    PH(CUR, 3, S3, VM2)                                                           \
  }

template <int MT, int NTOT, int KT>
__global__ __launch_bounds__(512, 2)
void k_gemm256(const __bf16* __restrict__ A, const __bf16* __restrict__ B,
               const float* __restrict__ bias, float* __restrict__ C) {
  __shared__ __align__(16) __bf16 sA[2][256 * 64];
  __shared__ __align__(16) __bf16 sB[2][256 * 64];

  const int tid = threadIdx.x;
  constexpr int nbm = MT / 256, nbn = NTOT / 256;
  // XCD bijective swizzle (grid % 8 == 0) + 4x16 supertile for L2 reuse
  int wg = blockIdx.x;
  { const int c = (nbm * nbn) >> 3; wg = (wg & 7) * c + (wg >> 3); }
  int bm, bn;
  if constexpr (nbm % 4 == 0 && nbn % 16 == 0) {
    constexpr int nstn = nbn / 16;
    const int st = wg >> 6, r = wg & 63;
    bm = (st / nstn) * 4 + (r >> 4);
    bn = (st % nstn) * 16 + (r & 15);
  } else {
    bm = wg / nbn; bn = wg % nbn;
  }
  const long m0 = (long)bm * 256, n0 = (long)bn * 256;

  const int lane = tid & 63, wid = tid >> 6;
  const int wm = wid >> 1, wn = wid & 1;      // 4 x 2 waves
  const int lr = lane & 15, lk = lane >> 4;
  const int swz = (lr & 7) << 4;

  auto stA = [&](int buf, int q, long knb, bool en) {
    if (!en) return;
    const int o = tid * 16;
    const int colb = (o & 127) ^ (((o >> 7) & 7) << 4);
    const long row = m0 + q * 64 + (o >> 7);
    gload_lds16((const char*)A + row * (KT * 2) + knb + colb,
                (char*)sA[buf] + q * 8192 + o);
  };
  auto stB = [&](int buf, int pr, long knb, bool en) {
    if (!en) return;
    const int o = tid * 16;
    const int colb = (o & 127) ^ (((o >> 7) & 7) << 4);
    const long col = n0 + pr * 64 + (o >> 7);
    gload_lds16((const char*)B + col * (KT * 2) + knb + colb,
                (char*)sB[buf] + pr * 8192 + o);
  };

  f32x4 acc[4][8] = {};

  // prologue: stage full tile 0 into buf 0 (order = steady-state order)
  stA(0, 0, 0, true); stA(0, 1, 0, true); stA(0, 2, 0, true); stA(0, 3, 0, true);
  stB(0, 0, 0, true); stB(0, 2, 0, true); stB(0, 1, 0, true); stB(0, 3, 0, true);
  asm volatile("s_waitcnt vmcnt(2)" ::: "memory");
  __builtin_amdgcn_s_barrier();

  constexpr int NTILES = KT / 64;
  for (int it = 0; it < NTILES / 2; ++it) {
    const long k1 = (long)(2 * it + 1) * 128;  // byte offset along K
    const long k2 = (long)(2 * it + 2) * 128;
    const bool s2 = (2 * it + 2) < NTILES;
    TILE(0,
         { stA(1, 0, k1, true); stA(1, 1, k1, true); },
         { stA(1, 2, k1, true); stA(1, 3, k1, true); },
         { stB(1, 0, k1, true); stB(1, 2, k1, true); },
         { stB(1, 1, k1, true); stB(1, 3, k1, true); })
    TILE(1,
         { stA(0, 0, k2, s2); stA(0, 1, k2, s2); },
         { stA(0, 2, k2, s2); stA(0, 3, k2, s2); },
         { stB(0, 0, k2, s2); stB(0, 2, k2, s2); },
         { stB(0, 1, k2, s2); stB(0, 3, k2, s2); })
  }

  // C/D layout: col = lane&15, row = (lane>>4)*4 + reg
#pragma unroll
  for (int nf = 0; nf < 8; ++nf) {
    const long col = n0 + wn * 128 + nf * 16 + lr;
    const float bv = bias[col];
#pragma unroll
    for (int mf = 0; mf < 4; ++mf) {
      const long r0r = m0 + wm * 64 + mf * 16 + lk * 4;
#pragma unroll
      for (int j = 0; j < 4; ++j)
        C[(r0r + j) * NTOT + col] = acc[mf][nf][j] + bv;
    }
  }
}

// ---------------- float <-> order-preserving u32 ----------------
__device__ __forceinline__ unsigned f2o(float f) {
  unsigned b = __float_as_uint(f);
  return ((int)b < 0) ? ~b : (b | 0x80000000u);
}
__device__ __forceinline__ float o2f(unsigned u) {
  unsigned b = (u & 0x80000000u) ? (u & 0x7FFFFFFFu) : ~u;
  return __uint_as_float(b);
}

// ---------------- per-row k-th largest: 2 global passes ----------------
// pass A: 2048-bin (11-bit) histogram + suffix scan -> threshold bin
// pass B: collect bin members to LDS, refine 21 bits in-LDS (8+8+5 radix)
__global__ __launch_bounds__(256)
void k_topk2(const float* __restrict__ z1, float* __restrict__ thr, int kwant) {
  __shared__ unsigned hist[2048];
  __shared__ unsigned cand[3584];
  __shared__ unsigned s_n, s_bin, s_rem, s_wt[4];
  const int tid = threadIdx.x;
  const long base = (long)blockIdx.x * NROWS_W;

#pragma unroll
  for (int j = 0; j < 8; ++j) hist[tid + j * 256] = 0;
  if (tid == 0) s_n = 0;
  __syncthreads();
  for (int i = tid; i < NROWS_W; i += 256)
    atomicAdd(&hist[f2o(z1[base + i]) >> 21], 1u);
  __syncthreads();
  unsigned p = 0;
#pragma unroll
  for (int j = 0; j < 8; ++j) p += hist[tid * 8 + j];
  // inclusive suffix over threads (thread t covers bins [t*8, t*8+8))
  unsigned sfx = p;
  const int lane = tid & 63, w = tid >> 6;
#pragma unroll
  for (int off = 1; off < 64; off <<= 1) {
    unsigned o = __shfl_down(sfx, off);
    sfx += (lane + off < 64) ? o : 0u;
  }
  if (lane == 0) s_wt[w] = sfx;
  __syncthreads();
  unsigned above_waves = 0;
  for (int ww = w + 1; ww < 4; ++ww) above_waves += s_wt[ww];
  const unsigned incl = sfx + above_waves;  // count in bins >= tid*8
  const int cnt = __syncthreads_count(incl >= (unsigned)kwant);
  const int tstar = cnt - 1;
  if (tid == tstar) {
    unsigned cum = incl - p;  // strictly above my bin range
    int bsel = tid * 8;
    for (int j = 7; j >= 0; --j) {
      const unsigned h = hist[tid * 8 + j];
      if (cum + h >= (unsigned)kwant) { bsel = tid * 8 + j; break; }
      cum += h;
    }
    s_bin = (unsigned)bsel;
    s_rem = (unsigned)kwant - cum;
  }
  __syncthreads();
  const unsigned binsel = s_bin;
  unsigned rem = s_rem;
  for (int i = tid; i < NROWS_W; i += 256) {
    const unsigned u = f2o(z1[base + i]);
    if ((u >> 21) == binsel) {
      const unsigned j = atomicAdd(&s_n, 1u);
      if (j < 3584u) cand[j] = u & 0x1FFFFFu;
    }
  }
  __syncthreads();
  const int n = (s_n < 3584u) ? (int)s_n : 3584;
  unsigned pfx = 0;
#pragma unroll
  for (int pass = 0; pass < 3; ++pass) {
    const int shift = (pass == 0) ? 13 : (pass == 1) ? 5 : 0;
    const int nb = (pass == 2) ? 32 : 256;
    if (tid < 256) hist[tid] = 0;
    __syncthreads();
    for (int i = tid; i < n; i += 256) {
      const unsigned v = cand[i];
      const bool m = (pass == 0) ? true
                     : (pass == 1) ? ((v >> 13) == (pfx >> 13))
                                   : ((v >> 5) == (pfx >> 5));
      if (m) atomicAdd(&hist[(v >> shift) & (nb - 1)], 1u);
    }
    __syncthreads();
    if (tid == 0) {
      unsigned cum = 0;
      int d = nb - 1;
      for (; d > 0; --d) {
        if (cum + hist[d] >= rem) break;
        cum += hist[d];
      }
      s_bin = (unsigned)d;
      s_rem = rem - cum;
    }
    __syncthreads();
    pfx |= (s_bin << shift);
    rem = s_rem;
    __syncthreads();
  }
  if (tid == 0) thr[blockIdx.x] = o2f((binsel << 21) | pfx);
}

// ---------------- zero band scratch ----------------
__global__ void k_zero(f32x4* __restrict__ p, int nvec) {
  int i = blockIdx.x * 256 + threadIdx.x;
  const int stride = gridDim.x * 256;
  f32x4 z = {0.f, 0.f, 0.f, 0.f};
  for (; i < nvec; i += stride) p[i] = z;
}

// ---------------- band pass: per-row scan ----------------
__global__ void k_band(const float* __restrict__ z1, const float* __restrict__ thr,
                       unsigned* __restrict__ rowlist, unsigned* __restrict__ rowcnt,
                       unsigned* __restrict__ c1, unsigned* __restrict__ bucket,
                       unsigned* __restrict__ bcnt) {
  const int b = blockIdx.x;
  const float t = thr[b];
  const float hi = t + DELTA, lo = t - DELTA;
  __shared__ unsigned s_above, s_cnt;
  if (threadIdx.x == 0) { s_above = 0; s_cnt = 0; }
  __syncthreads();
  unsigned my_above = 0;
  const long base = (long)b * NROWS_W;
  for (int i = threadIdx.x; i < NROWS_W; i += 256) {
    const float v = z1[base + i];
    my_above += (v > hi) ? 1u : 0u;
    if (v >= lo && v <= hi) {
      unsigned j = atomicAdd(&s_cnt, 1u);
      if (j < ROWCAP) {
        rowlist[(long)b * ROWCAP + j] = (unsigned)i;
        unsigned pq = atomicAdd(&bcnt[i], 1u);
        if (pq < HCAP) bucket[(long)i * HCAP + pq] = ((unsigned)b << 9) | j;
      }
    }
  }
  atomicAdd(&s_above, my_above);
  __syncthreads();
  if (threadIdx.x == 0) {
    rowcnt[b] = (s_cnt < ROWCAP) ? s_cnt : ROWCAP;
    c1[b] = s_above;
  }
}

// ---------------- h-major exact recompute ----------------
__global__ void k_recompute(const __bf16* __restrict__ Wh, const __bf16* __restrict__ Wl,
                            const __bf16* __restrict__ xh, const __bf16* __restrict__ xl,
                            const unsigned* __restrict__ bucket, const unsigned* __restrict__ bcnt,
                            float* __restrict__ exact) {
  const int h = blockIdx.x;
  unsigned n = bcnt[h];
  if (n > HCAP) n = HCAP;
  if (n == 0) return;
  __shared__ float wrec[DIM];
  const long wb = (long)h * DIM;
  for (int i = threadIdx.x; i < DIM; i += 256)
    wrec[i] = (float)Wh[wb + i] + (float)Wl[wb + i];
  __syncthreads();
  const int w = threadIdx.x >> 6, lane = threadIdx.x & 63;
  for (unsigned e = w; e < n; e += 4) {
    const unsigned ent = bucket[(long)h * HCAP + e];
    const int b = ent >> 9, j = ent & 511;
    const bf16x8* ph = (const bf16x8*)(xh + (long)b * DIM);
    const bf16x8* pl = (const bf16x8*)(xl + (long)b * DIM);
    float s = 0.f;
#pragma unroll
    for (int c = 0; c < 8; ++c) {
      const int i8 = c * 64 + lane;
      bf16x8 vh = ph[i8], vl = pl[i8];
      const float* wr = &wrec[i8 * 8];
#pragma unroll
      for (int q = 0; q < 8; ++q) s += ((float)vh[q] + (float)vl[q]) * wr[q];
    }
#pragma unroll
    for (int m = 32; m; m >>= 1) s += __shfl_xor(s, m);
    if (lane == 0) exact[(long)b * ROWCAP + j] = s;
  }
}

// ---------------- per-row select top (k - C1) among band -> bitmap ----------------
__global__ void k_select(const float* __restrict__ exact, const unsigned* __restrict__ rowlist,
                         const unsigned* __restrict__ rowcnt, const unsigned* __restrict__ c1,
                         unsigned* __restrict__ bitmap) {
  const int b = blockIdx.x;
  const int n = (int)rowcnt[b];
  const int need = KCNT - (int)c1[b];
  __shared__ float vals[ROWCAP];
  for (int j = threadIdx.x; j < ROWCAP; j += 256)
    vals[j] = (j < n) ? exact[(long)b * ROWCAP + j] : -1e30f;
  __syncthreads();
  for (int j = threadIdx.x; j < ROWCAP; j += 256) {
    if (j >= n) continue;
    const float vj = vals[j];
    int rank = 0;
    for (int i = 0; i < n; ++i) {
      const float vi = vals[i];
      rank += (vi > vj || (vi == vj && i < j)) ? 1 : 0;
    }
    if (rank < need) {
      const unsigned h = rowlist[(long)b * ROWCAP + j];
      atomicOr(&bitmap[b * (NROWS_W / 32) + (h >> 5)], 1u << (h & 31));
    }
  }
}

// ---------------- apply mask, write bf16 a1 ----------------
__global__ void k_mask(const float* __restrict__ z1, const float* __restrict__ thr,
                       const unsigned* __restrict__ bitmap, __bf16* __restrict__ a1,
                       int n4, int ncols4) {
  int i = blockIdx.x * 256 + threadIdx.x;
  const int stride = gridDim.x * 256;
  for (; i < n4; i += stride) {
    f32x4 v = ((const f32x4*)z1)[i];
    const int row = i / ncols4;
    const int h0 = (i - row * ncols4) * 4;
    const float t = thr[row];
    const float hi = t + DELTA, lo = t - DELTA;
    const unsigned wbits = bitmap[row * (NROWS_W / 32) + (h0 >> 5)];
    bf16x4 o;
#pragma unroll
    for (int j = 0; j < 4; ++j) {
      const float vv = v[j];
      const bool sel = (vv > hi) || (vv >= lo && ((wbits >> ((h0 + j) & 31)) & 1u));
      o[j] = sel ? (__bf16)vv : (__bf16)0.0f;
    }
    ((bf16x4*)a1)[i] = o;
  }
}

extern "C" void kernel_launch(void* const* d_in, const int* in_sizes, int n_in,
                              void* d_out, int out_size, void* d_ws, size_t ws_size,
                              hipStream_t stream) {
  const float* x     = (const float*)d_in[0];
  const float* W     = (const float*)d_in[1];
  const float* b_enc = (const float*)d_in[2];
  const float* b_dec = (const float*)d_in[3];
  float* out = (float*)d_out;

  const long NW = (long)NROWS_W * DIM;    // 134217728
  const long NX = (long)BATCH * DIM;      // 16777216
  const long NZ = (long)BATCH * NROWS_W;  // 134217728

  char* ws = (char*)d_ws;
  __bf16* Wh = (__bf16*)ws;        // 2*NW bytes
  __bf16* Wl = Wh + NW;            // 2*NW
  char*   btr = (char*)(Wl + NW);  // 2*NW region: band scratch, later Wt
  __bf16* Wt = (__bf16*)btr;       // written by transpose AFTER band phase
  __bf16* xh = (__bf16*)(btr + 2 * NW);  // 2*NX
  __bf16* xl = xh + NX;            // 2*NX
  float*  z1 = (float*)(xl + NX);  // 4*NZ
  float*  thr = z1 + NZ;           // 4*BATCH
  __bf16* a1 = Wl;                 // Wl dead after recompute -> reuse as a1

  unsigned* rowcnt  = (unsigned*)(btr);                 // 16 KB
  unsigned* c1      = (unsigned*)(btr + 16384);         // 16 KB
  unsigned* bcnt    = (unsigned*)(btr + 32768);         // 128 KB
  unsigned* bitmap  = (unsigned*)(btr + 163840);        // 16 MB
  float*    exact   = (float*)(btr + 16941056);         // 6 MB
  const long ZERO_BYTES = 23232512;                     // rowcnt..exact
  unsigned* rowlist = (unsigned*)(btr + 23232512);      // 6 MB
  unsigned* bucket  = (unsigned*)(btr + 29523968);      // 8 MB

  const size_t needed = (size_t)(6 * NW + 4 * NX) + (size_t)4 * NZ + 4 * BATCH;
  if (ws_size < needed) return;

  k_split<<<2048, 256, 0, stream>>>(W, Wh, Wl, (int)(NW / 4));
  k_split<<<2048, 256, 0, stream>>>(x, xh, xl, (int)(NX / 4));

  // encoder (approx): z1 = xh @ Wh^T + b_enc   [4096 x 32768]
  k_gemm256<BATCH, NROWS_W, DIM><<<(BATCH / 256) * (NROWS_W / 256), 512, 0, stream>>>(
      xh, Wh, b_enc, z1);

  k_topk2<<<BATCH, 256, 0, stream>>>(z1, thr, KCNT);

  k_zero<<<1024, 256, 0, stream>>>((f32x4*)btr, (int)(ZERO_BYTES / 16));
  k_band<<<BATCH, 256, 0, stream>>>(z1, thr, rowlist, rowcnt, c1, bucket, bcnt);
  k_recompute<<<NROWS_W, 256, 0, stream>>>(Wh, Wl, xh, xl, bucket, bcnt, exact);
  k_select<<<BATCH, 256, 0, stream>>>(exact, rowlist, rowcnt, c1, bitmap);
  k_mask<<<2048, 256, 0, stream>>>(z1, thr, bitmap, a1, (int)(NZ / 4), NROWS_W / 4);

  // band scratch dead; build Wt and decode
  k_transpose<<<dim3(DIM / 32, NROWS_W / 32), dim3(32, 8), 0, stream>>>(Wh, Wt, NROWS_W, DIM);
  k_gemm256<BATCH, DIM, NROWS_W><<<(BATCH / 256) * (DIM / 256), 512, 0, stream>>>(
      a1, Wt, b_dec, out);
}